// Round 11
// baseline (451.990 us; speedup 1.0000x reference)
//
#include <hip/hip_runtime.h>

#define N_NODES   50000
#define N_EDGES   600000
#define HID       128
#define N_GRAPHS  128
#define N_CLASSES 5
#define NCHUNK    ((N_NODES + 255) / 256)   // 196

// --- in-degree by dst ---
__global__ void k_deg(const int* __restrict__ dst, int* __restrict__ ideg, int E) {
    int i = blockIdx.x * blockDim.x + threadIdx.x;
    if (i < E) atomicAdd(&ideg[dst[i]], 1);
}

// --- per-chunk degree sums + dis = rsqrt(deg+1) ---
__global__ void k_scan_part(const int* __restrict__ ideg, int* __restrict__ bsum,
                            float* __restrict__ dis, int n) {
    __shared__ int s[256];
    int t = threadIdx.x;
    int i = blockIdx.x * 256 + t;
    int v = (i < n) ? ideg[i] : 0;
    if (i < n) dis[i] = 1.0f / sqrtf((float)v + 1.0f);
    s[t] = v;
    __syncthreads();
    for (int o = 128; o > 0; o >>= 1) { if (t < o) s[t] += s[t + o]; __syncthreads(); }
    if (t == 0) bsum[blockIdx.x] = s[0];
}

// --- single block: scan chunk sums -> boff, AND graph counts via binary search ---
__global__ void k_scan_bsum_goff(const int* __restrict__ bsum, int* __restrict__ boff,
                                 const int* __restrict__ batch, int* __restrict__ gcnt) {
    __shared__ int s[256];
    __shared__ int sgo[N_GRAPHS + 1];
    int t = threadIdx.x;
    int v = (t < NCHUNK) ? bsum[t] : 0;
    s[t] = v;
    __syncthreads();
    for (int o = 1; o < 256; o <<= 1) {
        int u = (t >= o) ? s[t - o] : 0; __syncthreads();
        s[t] += u; __syncthreads();
    }
    if (t < NCHUNK) boff[t] = s[t] - v;
    if (t == 255) boff[NCHUNK] = s[255];
    if (t <= N_GRAPHS) {
        int lo = 0, hi = N_NODES;
        while (lo < hi) { int mid = (lo + hi) >> 1; if (batch[mid] < t) lo = mid + 1; else hi = mid; }
        sgo[t] = lo;
    }
    __syncthreads();
    if (t < N_GRAPHS) gcnt[t] = sgo[t + 1] - sgo[t];
}

// --- per-chunk exclusive scan -> row_start ---
__global__ void k_scan_write(const int* __restrict__ ideg, const int* __restrict__ boff,
                             int* __restrict__ row_start, int n) {
    __shared__ int s[256];
    int t = threadIdx.x;
    int i = blockIdx.x * 256 + t;
    int v = (i < n) ? ideg[i] : 0;
    s[t] = v;
    __syncthreads();
    for (int o = 1; o < 256; o <<= 1) {
        int u = (t >= o) ? s[t - o] : 0; __syncthreads();
        s[t] += u; __syncthreads();
    }
    if (i < n) row_start[i] = boff[blockIdx.x] + s[t] - v;
    if (blockIdx.x == 0 && t == 0) row_start[n] = boff[NCHUNK];
}

// --- fused: CSR fill (first 600k threads) + layer-1 GEMM (all 1.6M threads) ---
__global__ void k_fill_gin(const int* __restrict__ src, const int* __restrict__ dst,
                           const int* __restrict__ rowst, int* __restrict__ cursor,
                           int* __restrict__ col,
                           const float* __restrict__ x, const float* __restrict__ W1,
                           const float* __restrict__ dis, float* __restrict__ out) {
    int gtid = blockIdx.x * 256 + threadIdx.x;
    if (gtid < N_EDGES) {
        int d = dst[gtid];
        int pos = atomicAdd(&cursor[d], 1);
        col[rowst[d] + pos] = src[gtid];
    }
    if (gtid < N_NODES * 32) {
        int row = gtid >> 5, c4 = (gtid & 31) * 4;
        float x0 = x[row * 3 + 0], x1 = x[row * 3 + 1], x2 = x[row * 3 + 2];
        float4 w0 = *(const float4*)&W1[0 * HID + c4];
        float4 w1 = *(const float4*)&W1[1 * HID + c4];
        float4 w2 = *(const float4*)&W1[2 * HID + c4];
        float dd = dis[row];
        float4 o;
        o.x = dd * fmaf(x2, w2.x, fmaf(x1, w1.x, x0 * w0.x));
        o.y = dd * fmaf(x2, w2.y, fmaf(x1, w1.y, x0 * w0.y));
        o.z = dd * fmaf(x2, w2.z, fmaf(x1, w1.z, x0 * w0.z));
        o.w = dd * fmaf(x2, w2.w, fmaf(x1, w1.w, x0 * w0.w));
        *(float4*)&out[(size_t)row * HID + c4] = o;
    }
}

// --- 128x128 GEMM (R6-proven): out = dis[:,None] * (h @ W), 64 rows/block ---
__global__ __launch_bounds__(256) void k_gemm64(const float* __restrict__ h,
                                                const float* __restrict__ W,
                                                const float* __restrict__ dis,
                                                float* __restrict__ out, int n) {
    __shared__ float Ws[2][8 * HID];
    int t  = threadIdx.x;
    int tc = t & 31;
    int tr = t >> 5;
    int rb = blockIdx.x * 64;
    int row0 = rb + tr * 8;
    int skk = t >> 5, sc4 = (t & 31) * 4;

    *(float4*)&Ws[0][skk * HID + sc4] = *(const float4*)&W[skk * HID + sc4];

    float acc[8][4];
#pragma unroll
    for (int r = 0; r < 8; ++r)
#pragma unroll
        for (int c = 0; c < 4; ++c) acc[r][c] = 0.f;

    int buf = 0;
    for (int k0 = 0; k0 < HID; k0 += 8) {
        float hr[8][8];
#pragma unroll
        for (int r = 0; r < 8; ++r) {
            int row = row0 + r; if (row >= n) row = n - 1;
            const float* hp = h + (size_t)row * HID + k0;
            float4 a = *(const float4*)hp;
            float4 b = *(const float4*)(hp + 4);
            hr[r][0] = a.x; hr[r][1] = a.y; hr[r][2] = a.z; hr[r][3] = a.w;
            hr[r][4] = b.x; hr[r][5] = b.y; hr[r][6] = b.z; hr[r][7] = b.w;
        }
        __syncthreads();
        if (k0 + 8 < HID)
            *(float4*)&Ws[buf ^ 1][skk * HID + sc4] =
                *(const float4*)&W[(k0 + 8 + skk) * HID + sc4];
#pragma unroll
        for (int kk = 0; kk < 8; ++kk) {
            float4 wv = *(const float4*)&Ws[buf][kk * HID + tc * 4];
#pragma unroll
            for (int r = 0; r < 8; ++r) {
                float hv = hr[r][kk];
                acc[r][0] = fmaf(hv, wv.x, acc[r][0]);
                acc[r][1] = fmaf(hv, wv.y, acc[r][1]);
                acc[r][2] = fmaf(hv, wv.z, acc[r][2]);
                acc[r][3] = fmaf(hv, wv.w, acc[r][3]);
            }
        }
        buf ^= 1;
    }
#pragma unroll
    for (int r = 0; r < 8; ++r) {
        int row = row0 + r;
        if (row < n) {
            float dd = dis[row];
            float4 o;
            o.x = dd * acc[r][0]; o.y = dd * acc[r][1];
            o.z = dd * acc[r][2]; o.w = dd * acc[r][3];
            *(float4*)&out[(size_t)row * HID + tc * 4] = o;
        }
    }
}

// --- aggregation, 1 dst per wave (4 dst/block, grid 12500 — max TLP; R6-proven).
// out[d] = relu(dis[d]*(t[d]+sum_{s in N(d)} t[s]) + b); POOL: atomicAdd into fpsum.
template <bool POOL>
__global__ __launch_bounds__(256) void k_agg(const float* __restrict__ t,
                                             const float* __restrict__ dis,
                                             const int* __restrict__ rowst,
                                             const int* __restrict__ col,
                                             const float* __restrict__ bias,
                                             const int* __restrict__ batch,
                                             float* __restrict__ fpsum,
                                             float* __restrict__ outp) {
    int lane = threadIdx.x & 63;
    int wid  = threadIdx.x >> 6;
    int d = blockIdx.x * 4 + wid;   // grid = N/4 = 12500 exactly
    const float2* t2 = (const float2*)t;
    float2 bv = ((const float2*)bias)[lane];
    float dd = dis[d];
    int j0 = rowst[d], j1 = rowst[d + 1];
    float2 self = t2[(size_t)d * 64 + lane];
    float ax0 = self.x, ay0 = self.y;
    float ax1 = 0.f, ay1 = 0.f, ax2 = 0.f, ay2 = 0.f, ax3 = 0.f, ay3 = 0.f;
    int j = j0;
    for (; j + 3 < j1; j += 4) {
        int s0 = col[j], s1 = col[j + 1], s2 = col[j + 2], s3 = col[j + 3];
        float2 v0 = t2[(size_t)s0 * 64 + lane];
        float2 v1 = t2[(size_t)s1 * 64 + lane];
        float2 v2 = t2[(size_t)s2 * 64 + lane];
        float2 v3 = t2[(size_t)s3 * 64 + lane];
        ax0 += v0.x; ay0 += v0.y;
        ax1 += v1.x; ay1 += v1.y;
        ax2 += v2.x; ay2 += v2.y;
        ax3 += v3.x; ay3 += v3.y;
    }
    for (; j < j1; ++j) {
        int s = col[j];
        float2 v = t2[(size_t)s * 64 + lane];
        ax0 += v.x; ay0 += v.y;
    }
    float sx = (ax0 + ax1) + (ax2 + ax3);
    float sy = (ay0 + ay1) + (ay2 + ay3);
    float zx = fmaxf(fmaf(dd, sx, bv.x), 0.f);
    float zy = fmaxf(fmaf(dd, sy, bv.y), 0.f);
    if (POOL) {
        int g = batch[d];
        atomicAdd(&fpsum[g * HID + 2 * lane], zx);
        atomicAdd(&fpsum[g * HID + 2 * lane + 1], zy);
    } else {
        float2 o; o.x = zx; o.y = zy;
        ((float2*)outp)[(size_t)d * 64 + lane] = o;
    }
}

// --- final linear with mean folded in ---
__global__ void k_final(const float* __restrict__ fpsum, const int* __restrict__ gcnt,
                        const float* __restrict__ Wl, const float* __restrict__ bl,
                        float* __restrict__ out) {
    int idx = blockIdx.x * blockDim.x + threadIdx.x;
    if (idx >= N_GRAPHS * N_CLASSES) return;
    int g = idx / N_CLASSES, c = idx % N_CLASSES;
    float inv = 1.0f / (float)max(gcnt[g], 1);
    float acc = bl[c];
    for (int f = 0; f < HID; ++f)
        acc = fmaf(fpsum[g * HID + f] * inv, Wl[f * N_CLASSES + c], acc);
    out[idx] = acc;
}

extern "C" void kernel_launch(void* const* d_in, const int* in_sizes, int n_in,
                              void* d_out, int out_size, void* d_ws, size_t ws_size,
                              hipStream_t stream) {
    const float* x     = (const float*)d_in[0];
    const int*   srcp  = (const int*)d_in[1];
    const int*   dstp  = (const int*)d_in[1] + N_EDGES;
    const int*   batch = (const int*)d_in[2];
    const float* W1 = (const float*)d_in[3];
    const float* b1 = (const float*)d_in[4];
    const float* W2 = (const float*)d_in[5];
    const float* b2 = (const float*)d_in[6];
    const float* W3 = (const float*)d_in[7];
    const float* b3 = (const float*)d_in[8];
    const float* Wl = (const float*)d_in[9];
    const float* bl = (const float*)d_in[10];
    float* out = (float*)d_out;

    const int N = N_NODES, E = N_EDGES;

    char* ws = (char*)d_ws;
    size_t off = 0;
    auto alloc = [&](size_t bytes) -> void* {
        void* p = ws + off;
        off += (bytes + 255) & ~(size_t)255;
        return p;
    };
    // zero-initialized region first & contiguous (ws is poisoned 0xAA each call)
    int*   ideg   = (int*)alloc((size_t)N * 4);
    int*   cursor = (int*)alloc((size_t)N * 4);
    float* fpsum  = (float*)alloc((size_t)N_GRAPHS * HID * 4);
    size_t zero_bytes = off;
    int*   gcnt  = (int*)alloc((size_t)N_GRAPHS * 4);
    float* dis   = (float*)alloc((size_t)N * 4);
    int*   rowst = (int*)alloc((size_t)(N + 1) * 4);
    int*   col   = (int*)alloc((size_t)E * 4);
    int*   bsum  = (int*)alloc((size_t)NCHUNK * 4);
    int*   boff  = (int*)alloc((size_t)(NCHUNK + 1) * 4);
    float* bufA  = (float*)alloc((size_t)N * HID * 4);
    float* bufB  = (float*)alloc((size_t)N * HID * 4);

    hipMemsetAsync(d_ws, 0, zero_bytes, stream);

    const int tpb = 256;
    k_deg<<<(E + tpb - 1) / tpb, tpb, 0, stream>>>(dstp, ideg, E);
    k_scan_part<<<NCHUNK, 256, 0, stream>>>(ideg, bsum, dis, N);
    k_scan_bsum_goff<<<1, 256, 0, stream>>>(bsum, boff, batch, gcnt);
    k_scan_write<<<NCHUNK, 256, 0, stream>>>(ideg, boff, rowst, N);
    // fill + layer-1 GEMM fused (independent work, one pass)
    k_fill_gin<<<N * 32 / tpb, tpb, 0, stream>>>(srcp, dstp, rowst, cursor, col,
                                                 x, W1, dis, bufA);
    // layer 1 agg
    k_agg<false><<<N / 4, 256, 0, stream>>>(bufA, dis, rowst, col, b1, batch, fpsum, bufB);
    // layer 2
    k_gemm64<<<(N + 63) / 64, 256, 0, stream>>>(bufB, W2, dis, bufA, N);
    k_agg<false><<<N / 4, 256, 0, stream>>>(bufA, dis, rowst, col, b2, batch, fpsum, bufB);
    // layer 3
    k_gemm64<<<(N + 63) / 64, 256, 0, stream>>>(bufB, W3, dis, bufA, N);
    k_agg<true><<<N / 4, 256, 0, stream>>>(bufA, dis, rowst, col, b3, batch, fpsum, nullptr);
    // classifier
    k_final<<<(N_GRAPHS * N_CLASSES + tpb - 1) / tpb, tpb, 0, stream>>>(fpsum, gcnt, Wl, bl, out);
}